// Round 8
// baseline (56.232 us; speedup 1.0000x reference)
//
#include <hip/hip_runtime.h>
#include <math.h>

// SimpleMamba: s_t = A*s_{t-1} + B*x_t ; y_t = tanh(C*s_t), per-channel.
// L=8192, D=2048, f32.
//
// R8: 3-kernel chunked scan, blocks restructured for contiguous streaming.
// One block = one FULL chunk (512 threads, 256 blocks): block footprint is a
// contiguous 256 KiB window of x (and of y), streamed row-by-row like the
// harness's 6.5 TB/s fill kernel (R7's half-chunk blocks covered 32 x 4 KiB
// strips at 8 KiB stride; p3 ran at only ~4.4 TB/s effective).
// Evidence recap: replay overhead ~2us (R6); p2 ~2.4us (R2->R3 delta); x re-read
// in p3 is L3-served (R6 FETCH=66MiB); nt-stores are neutral (R7).
// CL=32: p=A^32>0 (even power) -> inf carries propagate sign-stably, no inf-inf
// NaN; chunk-local sums stay finite (max|A|~3.9 -> 3.9^31*|Bx| ~ 1e20).
// Carry chain stays flat-serial (tree compose IS inf-inf NaN-unsafe).

#define LL 8192
#define DD 2048
#define CL 32
#define NC (LL / CL)   // 256 chunks = 256 blocks
#define G4 (DD / 4)    // 512 float4 channel-groups per row = threads per block

typedef float f32x4 __attribute__((ext_vector_type(4)));  // for nontemporal store

__device__ __forceinline__ float fast_tanh(float z)
{
    // tanh(z) = 1 - 2/(exp2(2z*log2e)+1); exact saturation at +-inf, ~1e-7 err.
    float e = __builtin_amdgcn_exp2f(z * 2.885390081777927f);
    return 1.0f - 2.0f * __builtin_amdgcn_rcpf(e + 1.0f);
}

// ---------------- Phase 1: per-chunk local end-state (from s=0) ----------------
// block = chunk; 512 threads each own one float4 column; block streams a
// contiguous 256 KiB x window.
__global__ __launch_bounds__(512) void mamba_p1(
    const float4* __restrict__ x4, const float4* __restrict__ A4,
    const float4* __restrict__ B4, float4* __restrict__ loc4)
{
    const int chunk = blockIdx.x;
    const int grp   = threadIdx.x;

    float4 a = A4[grp];
    float4 b = B4[grp];
    float sx = 0.f, sy = 0.f, sz = 0.f, sw = 0.f;

    const float4* xp = x4 + (size_t)chunk * CL * G4 + grp;
    #pragma unroll
    for (int t0 = 0; t0 < CL; t0 += 16) {
        float4 v[16];
        #pragma unroll
        for (int k = 0; k < 16; ++k)
            v[k] = xp[(size_t)(t0 + k) * G4];     // 16 dwordx4 in flight
        #pragma unroll
        for (int k = 0; k < 16; ++k) {
            sx = fmaf(a.x, sx, b.x * v[k].x);
            sy = fmaf(a.y, sy, b.y * v[k].y);
            sz = fmaf(a.z, sz, b.z * v[k].z);
            sw = fmaf(a.w, sw, b.w * v[k].w);
        }
    }
    loc4[(size_t)chunk * G4 + grp] = make_float4(sx, sy, sz, sw);
}

// ---------------- Phase 2: serial scan over chunks, one thread per CHANNEL ----------------
// carry[c] = state entering chunk c; carry[c+1] = A^CL * carry[c] + loc[c].
// 2048 threads over 32 blocks. 64-deep load batches -> 4 latency stalls.
// Measured ~2.4us; keep as-is.
__global__ __launch_bounds__(64) void mamba_p2(
    const float* __restrict__ A, const float* __restrict__ loc,
    float* __restrict__ car)
{
    int ch = blockIdx.x * 64 + threadIdx.x;       // 0..DD-1
    float p = A[ch];
    #pragma unroll
    for (int i = 0; i < 5; ++i) p *= p;           // A^32 > 0, finite

    float c = 0.f;
    for (int c0 = 0; c0 < NC; c0 += 64) {
        float lv[64];
        #pragma unroll
        for (int k = 0; k < 64; ++k)
            lv[k] = loc[(size_t)(c0 + k) * DD + ch];   // 64 loads in flight
        #pragma unroll
        for (int k = 0; k < 64; ++k) {
            car[(size_t)(c0 + k) * DD + ch] = c;
            c = fmaf(p, c, lv[k]);                     // p>0: inf stays sign-stable
        }
    }
}

// ---------------- Phase 3: recompute recurrence from carry, emit tanh(C*s) ----------------
// Same contiguous-block geometry as p1; y stores nontemporal (never re-read).
__global__ __launch_bounds__(512) void mamba_p3(
    const float4* __restrict__ x4, const float4* __restrict__ A4,
    const float4* __restrict__ B4, const float4* __restrict__ C4,
    const float4* __restrict__ car4, float4* __restrict__ y4)
{
    const int chunk = blockIdx.x;
    const int grp   = threadIdx.x;

    float4 a = A4[grp];
    float4 b = B4[grp];
    float4 c = C4[grp];
    float4 s0 = car4[(size_t)chunk * G4 + grp];
    float sx = s0.x, sy = s0.y, sz = s0.z, sw = s0.w;

    const float4* xp = x4 + (size_t)chunk * CL * G4 + grp;
    float4*       yp = y4 + (size_t)chunk * CL * G4 + grp;

    #pragma unroll
    for (int t0 = 0; t0 < CL; t0 += 16) {
        float4 v[16];
        #pragma unroll
        for (int k = 0; k < 16; ++k)
            v[k] = xp[(size_t)(t0 + k) * G4];     // 16 dwordx4 in flight (L3-warm)
        #pragma unroll
        for (int k = 0; k < 16; ++k) {
            sx = fmaf(a.x, sx, b.x * v[k].x);
            sy = fmaf(a.y, sy, b.y * v[k].y);
            sz = fmaf(a.z, sz, b.z * v[k].z);
            sw = fmaf(a.w, sw, b.w * v[k].w);
            f32x4 o;
            o.x = fast_tanh(c.x * sx);
            o.y = fast_tanh(c.y * sy);
            o.z = fast_tanh(c.z * sz);
            o.w = fast_tanh(c.w * sw);
            __builtin_nontemporal_store(o, (f32x4*)&yp[(size_t)(t0 + k) * G4]);
        }
    }
}

extern "C" void kernel_launch(void* const* d_in, const int* in_sizes, int n_in,
                              void* d_out, int out_size, void* d_ws, size_t ws_size,
                              hipStream_t stream)
{
    const float4* x4 = (const float4*)d_in[0];   // [L, D] f32
    const float*  Af = (const float*)d_in[1];
    const float4* A4 = (const float4*)d_in[1];   // [D]
    const float4* B4 = (const float4*)d_in[2];   // [D]
    const float4* C4 = (const float4*)d_in[3];   // [D]
    float4* y4 = (float4*)d_out;                 // [L, D] f32

    // workspace: loc (NC*D f32 = 2 MiB) + carry (2 MiB)
    float*  locf = (float*)d_ws;
    float4* loc4 = (float4*)d_ws;
    float*  carf = locf + (size_t)NC * DD;
    float4* car4 = (float4*)carf;

    mamba_p1<<<NC, 512, 0, stream>>>(x4, A4, B4, loc4);
    mamba_p2<<<DD / 64, 64, 0, stream>>>(Af, locf, carf);
    mamba_p3<<<NC, 512, 0, stream>>>(x4, A4, B4, C4, car4, y4);
}